// Round 1
// baseline (1379.810 us; speedup 1.0000x reference)
//
#include <hip/hip_runtime.h>
#include <math.h>

// Problem constants (from reference): N=8192 rows, C=32000 classes.
// DOWN_K=1.0 -> first top_k is a permutation (k1=N). TOP_K=0.6 -> k2=int(0.6*k1).
// Output = mean of the k2 largest per-row cross-entropy losses.

#define SORT_N 8192  // power of two >= N

__device__ __forceinline__ void ms_combine(float& m, float& s, float om, float os) {
    float M = fmaxf(m, om);
    // one of the exps is exp(0)=1; -inf inputs give exp(-inf)=0 safely
    s = s * __expf(m - M) + os * __expf(om - M);
    m = M;
}

// One block per row: online logsumexp over C floats, then loss = m + log(s) - x[target].
__global__ __launch_bounds__(256) void ce_row_loss(const float* __restrict__ x,
                                                   const int* __restrict__ tgt,
                                                   float* __restrict__ losses,
                                                   int C) {
    const int row = blockIdx.x;
    const float* __restrict__ xr = x + (size_t)row * (size_t)C;
    const float4* __restrict__ x4 = (const float4*)xr;
    const int n4 = C >> 2;

    float m = -INFINITY;
    float s = 0.f;

    for (int i = threadIdx.x; i < n4; i += blockDim.x) {
        float4 v = x4[i];
        float vv[4] = {v.x, v.y, v.z, v.w};
#pragma unroll
        for (int j = 0; j < 4; ++j) {
            float xv = vv[j];
            if (xv <= m) {
                s += __expf(xv - m);          // common path: 1 exp
            } else {
                s = s * __expf(m - xv) + 1.f; // rare rescale path (~log n times)
                m = xv;
            }
        }
    }
    // scalar tail (C % 4 != 0 safety; C=32000 -> empty)
    for (int i = (n4 << 2) + threadIdx.x; i < C; i += blockDim.x) {
        float xv = xr[i];
        if (xv <= m) s += __expf(xv - m);
        else { s = s * __expf(m - xv) + 1.f; m = xv; }
    }

    // wave-64 butterfly reduce of (m, s)
#pragma unroll
    for (int off = 32; off > 0; off >>= 1) {
        float om = __shfl_xor(m, off, 64);
        float os = __shfl_xor(s, off, 64);
        ms_combine(m, s, om, os);
    }

    __shared__ float sm[4];
    __shared__ float ss[4];
    const int wave = threadIdx.x >> 6;
    if ((threadIdx.x & 63) == 0) { sm[wave] = m; ss[wave] = s; }
    __syncthreads();

    if (threadIdx.x == 0) {
        float M = sm[0], S = ss[0];
        const int nw = (int)(blockDim.x >> 6);
        for (int w = 1; w < nw; ++w) ms_combine(M, S, sm[w], ss[w]);
        const int t = tgt[row];
        losses[row] = M + logf(S) - xr[t];
    }
}

// Single block: bitonic-sort N losses in LDS (ascending), mean of last k.
__global__ __launch_bounds__(1024) void topk_mean(const float* __restrict__ losses,
                                                  float* __restrict__ out,
                                                  int n, int k) {
    __shared__ float sd[SORT_N];
    const int tid = threadIdx.x;

    for (int i = tid; i < SORT_N; i += 1024)
        sd[i] = (i < n) ? losses[i] : -INFINITY;
    __syncthreads();

    for (int ksz = 2; ksz <= SORT_N; ksz <<= 1) {
        for (int j = ksz >> 1; j > 0; j >>= 1) {
            for (int i = tid; i < SORT_N; i += 1024) {
                const int ixj = i ^ j;
                if (ixj > i) {
                    const bool up = ((i & ksz) == 0);
                    float a = sd[i];
                    float b = sd[ixj];
                    if ((a > b) == up) { sd[i] = b; sd[ixj] = a; }
                }
            }
            __syncthreads();
        }
    }

    // ascending order: the k largest are sd[SORT_N-k .. SORT_N-1]
    float p = 0.f;
    for (int i = (SORT_N - k) + tid; i < SORT_N; i += 1024) p += sd[i];
#pragma unroll
    for (int off = 32; off > 0; off >>= 1) p += __shfl_xor(p, off, 64);

    __shared__ float sp[16];
    const int wave = tid >> 6;
    if ((tid & 63) == 0) sp[wave] = p;
    __syncthreads();

    if (tid == 0) {
        float tot = 0.f;
#pragma unroll
        for (int w = 0; w < 16; ++w) tot += sp[w];
        out[0] = tot / (float)k;
    }
}

extern "C" void kernel_launch(void* const* d_in, const int* in_sizes, int n_in,
                              void* d_out, int out_size, void* d_ws, size_t ws_size,
                              hipStream_t stream) {
    const float* x   = (const float*)d_in[0];
    const int*   tgt = (const int*)d_in[1];
    float*       out = (float*)d_out;

    const int N = in_sizes[1];          // 8192
    const int C = in_sizes[0] / N;      // 32000

    float* losses = (float*)d_ws;       // N floats = 32 KB scratch

    ce_row_loss<<<N, 256, 0, stream>>>(x, tgt, losses, C);

    const int k1 = (int)(1.0 * (double)N);   // DOWN_K = 1.0
    const int k2 = (int)(0.6 * (double)k1);  // TOP_K  = 0.6 -> 4915

    topk_mean<<<1, 1024, 0, stream>>>(losses, out, N, k2);
}